// Round 12
// baseline (82.033 us; speedup 1.0000x reference)
//
#include <hip/hip_runtime.h>

#define S 512
#define Dm 512

typedef __bf16 bf16x8 __attribute__((ext_vector_type(8)));
typedef float f32x4 __attribute__((ext_vector_type(4)));

// ---------------- bf16 MFMA GEMM with inline fp32->bf16 conversion ----------------
template<bool A_BF16>
__global__ __launch_bounds__(256) void gemm_icvt(
    const void* __restrict__ Aptr,
    const float* __restrict__ W0, const float* __restrict__ W1, const float* __restrict__ W2,
    const float* __restrict__ b0, const float* __restrict__ b1, const float* __restrict__ b2,
    float* __restrict__ O0, float* __restrict__ O1, float* __restrict__ O2)
{
    int blk = blockIdx.x;
    int m = blk >> 8;
    int tile = blk & 255;
    const float* W = (m == 0) ? W0 : (m == 1) ? W1 : W2;
    const float* bias = (m == 0) ? b0 : (m == 1) ? b1 : b2;
    float* O = (m == 0) ? O0 : (m == 1) ? O1 : O2;
    int rt = tile >> 4, ct = tile & 15;

    int u = threadIdx.x;
    int w = u >> 6, lane = u & 63;
    int r = lane & 15, kg = lane >> 4;

    int row0 = (rt << 5) + ((w >> 1) << 4);
    int col0 = (ct << 5) + ((w & 1) << 4);

    const float* Bp = W + (kg << 3) * Dm + col0 + r;

    f32x4 acc = {0.f, 0.f, 0.f, 0.f};

    #pragma unroll 4
    for (int k0 = 0; k0 < Dm; k0 += 32) {
        bf16x8 a;
        if constexpr (A_BF16) {
            const __bf16* Ab = (const __bf16*)Aptr;
            a = *(const bf16x8*)(Ab + (row0 + r) * Dm + k0 + (kg << 3));
        } else {
            const float* Af = (const float*)Aptr;
            float4 a0 = *(const float4*)(Af + (row0 + r) * Dm + k0 + (kg << 3));
            float4 a1 = *(const float4*)(Af + (row0 + r) * Dm + k0 + (kg << 3) + 4);
            a[0] = (__bf16)a0.x; a[1] = (__bf16)a0.y; a[2] = (__bf16)a0.z; a[3] = (__bf16)a0.w;
            a[4] = (__bf16)a1.x; a[5] = (__bf16)a1.y; a[6] = (__bf16)a1.z; a[7] = (__bf16)a1.w;
        }
        bf16x8 b;
        #pragma unroll
        for (int t = 0; t < 8; ++t)
            b[t] = (__bf16)Bp[(k0 + t) * Dm];
        acc = __builtin_amdgcn_mfma_f32_16x16x32_bf16(a, b, acc, 0, 0, 0);
    }

    int orow = row0 + (kg << 2);
    float bb = bias[col0 + r];
    #pragma unroll
    for (int t = 0; t < 4; ++t)
        O[(orow + t) * Dm + col0 + r] = acc[t] + bb;
}

// true opaque zero: stays 0 but compiler can't prove it's wave-uniform
__device__ __forceinline__ int opaque_zero() {
    int lz = 0;
    asm volatile("" : "+v"(lz));
    return lz;
}

// ---------------- z-pass: lane = i, Q-row in VGPRs, K row BATCH-loaded per j ----------------
// grid 1024 = 8 heads * 8 i-tiles(64) * 16 j-tiles(32). 256 thr = 4 waves; wave w: 8 j's.
// Per j: 16 float4 loads all in flight (one wait), then 128 pure-VALU ops.
__global__ __launch_bounds__(256) void zfast_kernel(
    const float* __restrict__ Q, const float* __restrict__ K,
    const float* __restrict__ mask, const float* __restrict__ gamma,
    const float* __restrict__ alpha,
    float* __restrict__ zp, float* __restrict__ Zpart)
{
    int blk = blockIdx.x;
    int h  = blk >> 7;
    int it = (blk >> 4) & 7;
    int jt = blk & 15;
    int i0 = it << 6;
    int j0 = jt << 5;
    int c0 = h << 6;

    int u = threadIdx.x;
    int w = u >> 6, lane = u & 63;

    __shared__ float zsT[32][65];
    __shared__ float partial[4][64];

    int lz = opaque_zero();

    float qreg[64];
    #pragma unroll
    for (int t = 0; t < 16; ++t) {
        float4 qv = *(const float4*)(Q + (i0 + lane) * Dm + c0 + (t << 2));
        qreg[4 * t + 0] = qv.x; qreg[4 * t + 1] = qv.y;
        qreg[4 * t + 2] = qv.z; qreg[4 * t + 3] = qv.w;
    }

    float sc = 1.0f / (gamma[0] * 8.0f);
    float al = alpha[0];

    int jb = w << 3;
    float zsum = 0.f;

    #pragma unroll 1
    for (int jj = 0; jj < 8; ++jj) {
        int j = j0 + jb + jj;
        const float* kr = K + j * Dm + c0 + lz;
        float madd = (1.0f - mask[j + lz]) * 1e6f;

        // ---- batch load: 16 float4, all outstanding together ----
        float4 kv[16];
        #pragma unroll
        for (int t = 0; t < 16; ++t)
            kv[t] = *(const float4*)(kr + (t << 2));

        // ---- pure-VALU burst: 128 ops, 4 independent chains ----
        float a0 = 0.f, a1 = 0.f, a2 = 0.f, a3 = 0.f;
        #pragma unroll
        for (int t = 0; t < 16; ++t) {
            a0 += fabsf(qreg[4 * t + 0] - kv[t].x);
            a1 += fabsf(qreg[4 * t + 1] - kv[t].y);
            a2 += fabsf(qreg[4 * t + 2] - kv[t].z);
            a3 += fabsf(qreg[4 * t + 3] - kv[t].w);
        }
        float zpv = fmaxf((a0 + a1 + a2 + a3) * sc - al, 0.0f) + madd;
        zsT[jb + jj][lane] = zpv;
        zsum += zpv;
    }
    partial[w][lane] = zsum;
    __syncthreads();

    if (u < 64) {
        float zs4 = 0.f;
        #pragma unroll
        for (int p = 0; p < 4; ++p) zs4 += partial[p][u];
        Zpart[((h << 9) + i0 + u) * 16 + jt] = zs4;
    }

    // transposed, coalesced zp write: thread -> row, 8 consecutive j
    {
        int row = u >> 2;              // 0..63
        int jg = (u & 3) << 3;         // 0,8,16,24
        float* orow = zp + ((h << 9) + i0 + row) * S + j0 + jg;
        #pragma unroll
        for (int q4 = 0; q4 < 2; ++q4) {
            float4 o;
            o.x = zsT[jg + (q4 << 2) + 0][row];
            o.y = zsT[jg + (q4 << 2) + 1][row];
            o.z = zsT[jg + (q4 << 2) + 2][row];
            o.w = zsT[jg + (q4 << 2) + 3][row];
            *(float4*)(orow + (q4 << 2)) = o;
        }
    }
}

// ---------------- ctx: ctx[i][d] = sum_j max(v,z') - Zsum, batched z loads ----------------
// grid 512 = 8 heads * 64 i-tiles(8). 256 thr = 4 waves; lane = d; wave w: 16-j slice per cch.
__global__ __launch_bounds__(256) void ctx_kernel(
    const float* __restrict__ V, const float* __restrict__ zp,
    const float* __restrict__ Zpart, __bf16* __restrict__ ctxb)
{
    int blk = blockIdx.x;
    int h = blk >> 6;
    int it = blk & 63;
    int i0 = it << 3;
    int c0 = h << 6;
    int u = threadIdx.x;
    int w = u >> 6, lane = u & 63;

    __shared__ float part[4][8][64];

    int lz = opaque_zero();
    int wu = __builtin_amdgcn_readfirstlane(w);
    float acc[8][4] = {};

    #pragma unroll 1
    for (int cch = 0; cch < 8; ++cch) {
        int jg = (cch << 6) + (wu << 4);
        // batch V loads (per-lane coalesced)
        float vv[16];
        #pragma unroll
        for (int t = 0; t < 16; ++t)
            vv[t] = V[(jg + t) * Dm + c0 + lane];

        const float* zbase = zp + ((h << 9) + i0) * S + jg + lz;
        #pragma unroll
        for (int q4 = 0; q4 < 4; ++q4) {
            // ---- batch 8 z-row float4s, one wait ----
            float4 zr[8];
            #pragma unroll
            for (int ii = 0; ii < 8; ++ii)
                zr[ii] = *(const float4*)(zbase + ii * S + (q4 << 2));
            // ---- 64 pure-VALU ops ----
            #pragma unroll
            for (int ii = 0; ii < 8; ++ii) {
                acc[ii][0] += fmaxf(vv[(q4 << 2) + 0], zr[ii].x);
                acc[ii][1] += fmaxf(vv[(q4 << 2) + 1], zr[ii].y);
                acc[ii][2] += fmaxf(vv[(q4 << 2) + 2], zr[ii].z);
                acc[ii][3] += fmaxf(vv[(q4 << 2) + 3], zr[ii].w);
            }
        }
    }

    #pragma unroll
    for (int ii = 0; ii < 8; ++ii)
        part[w][ii][lane] = (acc[ii][0] + acc[ii][1]) + (acc[ii][2] + acc[ii][3]);
    __syncthreads();

    #pragma unroll
    for (int rep = 0; rep < 2; ++rep) {
        int ii = (u >> 6) + (rep << 2);      // 0..3 then 4..7
        float s = 0.f;
        #pragma unroll
        for (int ww = 0; ww < 4; ++ww) s += part[ww][ii][lane];
        float zsum = 0.f;
        const float* zpr = Zpart + ((h << 9) + (i0 + ii)) * 16;
        #pragma unroll
        for (int p = 0; p < 16; ++p) zsum += zpr[p];
        ctxb[(i0 + ii) * Dm + c0 + lane] = (__bf16)(s - zsum);
    }
}

extern "C" void kernel_launch(void* const* d_in, const int* in_sizes, int n_in,
                              void* d_out, int out_size, void* d_ws, size_t ws_size,
                              hipStream_t stream) {
    const float* hs    = (const float*)d_in[0];
    const float* mask  = (const float*)d_in[1];
    const float* Wq    = (const float*)d_in[2];
    const float* bq    = (const float*)d_in[3];
    const float* Wk    = (const float*)d_in[4];
    const float* bk    = (const float*)d_in[5];
    const float* Wv    = (const float*)d_in[6];
    const float* bv    = (const float*)d_in[7];
    const float* Wo    = (const float*)d_in[8];
    const float* bo    = (const float*)d_in[9];
    const float* gamma = (const float*)d_in[10];
    const float* alpha = (const float*)d_in[11];
    float* out = (float*)d_out;

    char* base = (char*)d_ws;
    float*  zp    = (float*)(base);                               // 8 MB
    float*  Zpart = (float*)(base + (8u << 20));                  // 256 KB
    float*  Qb    = (float*)(base + (8u << 20) + (256u << 10));   // 1 MB
    float*  Kb    = Qb + S * Dm;                                  // 1 MB
    float*  Vb    = Kb + S * Dm;                                  // 1 MB
    __bf16* Cbf   = (__bf16*)(Vb + S * Dm);                       // 0.5 MB

    hipLaunchKernelGGL((gemm_icvt<false>), dim3(768), dim3(256), 0, stream,
                       (const void*)hs, Wq, Wk, Wv, bq, bk, bv, Qb, Kb, Vb);
    hipLaunchKernelGGL(zfast_kernel, dim3(1024), dim3(256), 0, stream,
                       Qb, Kb, mask, gamma, alpha, zp, Zpart);
    hipLaunchKernelGGL(ctx_kernel, dim3(512), dim3(256), 0, stream,
                       Vb, zp, Zpart, Cbf);
    hipLaunchKernelGGL((gemm_icvt<true>), dim3(256), dim3(256), 0, stream,
                       (const void*)Cbf, Wo, Wo, Wo, bo, bo, bo, out, out, out);
}

// Round 13
// 71.059 us; speedup vs baseline: 1.1544x; 1.1544x over previous
//
#include <hip/hip_runtime.h>

#define S 512
#define Dm 512

typedef __bf16 bf16x8 __attribute__((ext_vector_type(8)));
typedef float f32x4 __attribute__((ext_vector_type(4)));

// ---------------- bf16 MFMA GEMM with inline fp32->bf16 conversion ----------------
template<bool A_BF16>
__global__ __launch_bounds__(256) void gemm_icvt(
    const void* __restrict__ Aptr,
    const float* __restrict__ W0, const float* __restrict__ W1, const float* __restrict__ W2,
    const float* __restrict__ b0, const float* __restrict__ b1, const float* __restrict__ b2,
    float* __restrict__ O0, float* __restrict__ O1, float* __restrict__ O2)
{
    int blk = blockIdx.x;
    int m = blk >> 8;
    int tile = blk & 255;
    const float* W = (m == 0) ? W0 : (m == 1) ? W1 : W2;
    const float* bias = (m == 0) ? b0 : (m == 1) ? b1 : b2;
    float* O = (m == 0) ? O0 : (m == 1) ? O1 : O2;
    int rt = tile >> 4, ct = tile & 15;

    int u = threadIdx.x;
    int w = u >> 6, lane = u & 63;
    int r = lane & 15, kg = lane >> 4;

    int row0 = (rt << 5) + ((w >> 1) << 4);
    int col0 = (ct << 5) + ((w & 1) << 4);

    const float* Bp = W + (kg << 3) * Dm + col0 + r;

    f32x4 acc = {0.f, 0.f, 0.f, 0.f};

    #pragma unroll 4
    for (int k0 = 0; k0 < Dm; k0 += 32) {
        bf16x8 a;
        if constexpr (A_BF16) {
            const __bf16* Ab = (const __bf16*)Aptr;
            a = *(const bf16x8*)(Ab + (row0 + r) * Dm + k0 + (kg << 3));
        } else {
            const float* Af = (const float*)Aptr;
            float4 a0 = *(const float4*)(Af + (row0 + r) * Dm + k0 + (kg << 3));
            float4 a1 = *(const float4*)(Af + (row0 + r) * Dm + k0 + (kg << 3) + 4);
            a[0] = (__bf16)a0.x; a[1] = (__bf16)a0.y; a[2] = (__bf16)a0.z; a[3] = (__bf16)a0.w;
            a[4] = (__bf16)a1.x; a[5] = (__bf16)a1.y; a[6] = (__bf16)a1.z; a[7] = (__bf16)a1.w;
        }
        bf16x8 b;
        #pragma unroll
        for (int t = 0; t < 8; ++t)
            b[t] = (__bf16)Bp[(k0 + t) * Dm];
        acc = __builtin_amdgcn_mfma_f32_16x16x32_bf16(a, b, acc, 0, 0, 0);
    }

    int orow = row0 + (kg << 2);
    float bb = bias[col0 + r];
    #pragma unroll
    for (int t = 0; t < 4; ++t)
        O[(orow + t) * Dm + col0 + r] = acc[t] + bb;
}

// ---------------- z-pass (r8): lane = i, Q-row in VGPRs, K via wave-uniform scalar loads ----------------
// grid 512 = 8 heads * 8 i-tiles(64) * 8 j-tiles(64). 512 thr = 8 waves; wave w: 8 j's.
__global__ __launch_bounds__(512) void zfast_kernel(
    const float* __restrict__ Q, const float* __restrict__ K,
    const float* __restrict__ mask, const float* __restrict__ gamma,
    const float* __restrict__ alpha,
    float* __restrict__ zp, float* __restrict__ Zpart)
{
    int blk = blockIdx.x;
    int h  = blk >> 6;
    int it = (blk >> 3) & 7;
    int jt = blk & 7;
    int i0 = it << 6;
    int j0 = jt << 6;
    int c0 = h << 6;

    int u = threadIdx.x;
    int w = u >> 6, lane = u & 63;

    __shared__ float zsT[64][65];
    __shared__ float partial[8][64];

    float qreg[64];
    #pragma unroll
    for (int t = 0; t < 16; ++t) {
        float4 qv = *(const float4*)(Q + (i0 + lane) * Dm + c0 + (t << 2));
        qreg[4 * t + 0] = qv.x; qreg[4 * t + 1] = qv.y;
        qreg[4 * t + 2] = qv.z; qreg[4 * t + 3] = qv.w;
    }

    float sc = 1.0f / (gamma[0] * 8.0f);
    float al = alpha[0];

    int jb = __builtin_amdgcn_readfirstlane(w << 3);

    float zsum = 0.f;
    #pragma unroll 2
    for (int jj = 0; jj < 8; ++jj) {
        const float* kr = K + (j0 + jb + jj) * Dm + c0;   // uniform pointer -> SMEM
        float a0 = 0.f, a1 = 0.f, a2 = 0.f, a3 = 0.f;
        #pragma unroll
        for (int t = 0; t < 16; ++t) {
            float4 kb = *(const float4*)(kr + (t << 2));
            a0 += fabsf(qreg[4 * t + 0] - kb.x);
            a1 += fabsf(qreg[4 * t + 1] - kb.y);
            a2 += fabsf(qreg[4 * t + 2] - kb.z);
            a3 += fabsf(qreg[4 * t + 3] - kb.w);
        }
        float madd = (1.0f - mask[j0 + jb + jj]) * 1e6f;
        float zpv = fmaxf((a0 + a1 + a2 + a3) * sc - al, 0.0f) + madd;
        zsT[jb + jj][lane] = zpv;
        zsum += zpv;
    }
    partial[w][lane] = zsum;
    __syncthreads();

    if (u < 64) {
        float zs8 = 0.f;
        #pragma unroll
        for (int p = 0; p < 8; ++p) zs8 += partial[p][u];
        Zpart[((h << 9) + i0 + u) * 8 + jt] = zs8;
    }

    {
        int il = u >> 3;
        int jg = (u & 7) << 3;
        float* orow = zp + ((h << 9) + i0 + il) * S + j0 + jg;
        #pragma unroll
        for (int q4 = 0; q4 < 2; ++q4) {
            float4 o;
            o.x = zsT[jg + (q4 << 2) + 0][il];
            o.y = zsT[jg + (q4 << 2) + 1][il];
            o.z = zsT[jg + (q4 << 2) + 2][il];
            o.w = zsT[jg + (q4 << 2) + 3][il];
            *(float4*)(orow + (q4 << 2)) = o;
        }
    }
}

// ---------------- ctx: 16-i tiles -> 2x VALU per V-load (TA relief) ----------------
// grid 256 = 8 heads * 32 i-tiles(16 rows). 512 thr = 8 waves; lane = d.
// Per cch: wave slice of 16 j; vv[16] per-lane V loads reused across 16 i-rows;
// z' rows via wave-uniform scalar loads. ctx = sum - Zsum, bf16 out.
__global__ __launch_bounds__(512) void ctx_kernel(
    const float* __restrict__ V, const float* __restrict__ zp,
    const float* __restrict__ Zpart, __bf16* __restrict__ ctxb)
{
    int blk = blockIdx.x;
    int h = blk >> 5;
    int it = blk & 31;
    int i0 = it << 4;
    int c0 = h << 6;
    int u = threadIdx.x;
    int w = u >> 6, lane = u & 63;

    __shared__ float part[8][16][64];   // 32 KB

    int wu = __builtin_amdgcn_readfirstlane(w);
    float acc[16][4] = {};

    #pragma unroll 1
    for (int cch = 0; cch < 4; ++cch) {
        int jg = (cch << 7) + (wu << 4);                    // uniform
        float vv[16];
        #pragma unroll
        for (int t = 0; t < 16; ++t)
            vv[t] = V[(jg + t) * Dm + c0 + lane];           // coalesced b32

        const float* zbase = zp + ((h << 9) + i0) * S + jg; // uniform -> SMEM
        #pragma unroll
        for (int ii = 0; ii < 16; ++ii) {
            const float* zrow = zbase + ii * S;
            #pragma unroll
            for (int q4 = 0; q4 < 4; ++q4) {
                float4 z4 = *(const float4*)(zrow + (q4 << 2));
                acc[ii][0] += fmaxf(vv[(q4 << 2) + 0], z4.x);
                acc[ii][1] += fmaxf(vv[(q4 << 2) + 1], z4.y);
                acc[ii][2] += fmaxf(vv[(q4 << 2) + 2], z4.z);
                acc[ii][3] += fmaxf(vv[(q4 << 2) + 3], z4.w);
            }
        }
    }

    #pragma unroll
    for (int ii = 0; ii < 16; ++ii)
        part[w][ii][lane] = (acc[ii][0] + acc[ii][1]) + (acc[ii][2] + acc[ii][3]);
    __syncthreads();

    #pragma unroll
    for (int rep = 0; rep < 2; ++rep) {
        int ii = (u >> 6) + (rep << 3);      // 0..7 then 8..15
        float s = 0.f;
        #pragma unroll
        for (int ww = 0; ww < 8; ++ww) s += part[ww][ii][lane];
        float zsum = 0.f;
        const float* zpr = Zpart + ((h << 9) + (i0 + ii)) * 8;
        #pragma unroll
        for (int p = 0; p < 8; ++p) zsum += zpr[p];
        ctxb[(i0 + ii) * Dm + c0 + lane] = (__bf16)(s - zsum);
    }
}

extern "C" void kernel_launch(void* const* d_in, const int* in_sizes, int n_in,
                              void* d_out, int out_size, void* d_ws, size_t ws_size,
                              hipStream_t stream) {
    const float* hs    = (const float*)d_in[0];
    const float* mask  = (const float*)d_in[1];
    const float* Wq    = (const float*)d_in[2];
    const float* bq    = (const float*)d_in[3];
    const float* Wk    = (const float*)d_in[4];
    const float* bk    = (const float*)d_in[5];
    const float* Wv    = (const float*)d_in[6];
    const float* bv    = (const float*)d_in[7];
    const float* Wo    = (const float*)d_in[8];
    const float* bo    = (const float*)d_in[9];
    const float* gamma = (const float*)d_in[10];
    const float* alpha = (const float*)d_in[11];
    float* out = (float*)d_out;

    char* base = (char*)d_ws;
    float*  zp    = (float*)(base);                               // 8 MB
    float*  Zpart = (float*)(base + (8u << 20));                  // 128 KB
    float*  Qb    = (float*)(base + (8u << 20) + (128u << 10));   // 1 MB
    float*  Kb    = Qb + S * Dm;                                  // 1 MB
    float*  Vb    = Kb + S * Dm;                                  // 1 MB
    __bf16* Cbf   = (__bf16*)(Vb + S * Dm);                       // 0.5 MB

    hipLaunchKernelGGL((gemm_icvt<false>), dim3(768), dim3(256), 0, stream,
                       (const void*)hs, Wq, Wk, Wv, bq, bk, bv, Qb, Kb, Vb);
    hipLaunchKernelGGL(zfast_kernel, dim3(512), dim3(512), 0, stream,
                       Qb, Kb, mask, gamma, alpha, zp, Zpart);
    hipLaunchKernelGGL(ctx_kernel, dim3(256), dim3(512), 0, stream,
                       Vb, zp, Zpart, Cbf);
    hipLaunchKernelGGL((gemm_icvt<true>), dim3(256), dim3(256), 0, stream,
                       (const void*)Cbf, Wo, Wo, Wo, bo, bo, bo, out, out, out);
}

// Round 14
// 64.792 us; speedup vs baseline: 1.2661x; 1.0967x over previous
//
#include <hip/hip_runtime.h>

#define S 512
#define Dm 512

typedef __bf16 bf16x8 __attribute__((ext_vector_type(8)));
typedef float f32x4 __attribute__((ext_vector_type(4)));

__device__ __forceinline__ float bflo(unsigned int u) { return __uint_as_float(u << 16); }
__device__ __forceinline__ float bfhi(unsigned int u) { return __uint_as_float(u & 0xffff0000u); }

// ---------------- bf16 MFMA GEMM with inline fp32->bf16 conversion ----------------
// m==1 (K) additionally writes a bf16 mirror for the z-pass scalar loads.
template<bool A_BF16>
__global__ __launch_bounds__(256) void gemm_icvt(
    const void* __restrict__ Aptr,
    const float* __restrict__ W0, const float* __restrict__ W1, const float* __restrict__ W2,
    const float* __restrict__ b0, const float* __restrict__ b1, const float* __restrict__ b2,
    float* __restrict__ O0, float* __restrict__ O1, float* __restrict__ O2,
    __bf16* __restrict__ Kbf)
{
    int blk = blockIdx.x;
    int m = blk >> 8;
    int tile = blk & 255;
    const float* W = (m == 0) ? W0 : (m == 1) ? W1 : W2;
    const float* bias = (m == 0) ? b0 : (m == 1) ? b1 : b2;
    float* O = (m == 0) ? O0 : (m == 1) ? O1 : O2;
    int rt = tile >> 4, ct = tile & 15;

    int u = threadIdx.x;
    int w = u >> 6, lane = u & 63;
    int r = lane & 15, kg = lane >> 4;

    int row0 = (rt << 5) + ((w >> 1) << 4);
    int col0 = (ct << 5) + ((w & 1) << 4);

    const float* Bp = W + (kg << 3) * Dm + col0 + r;

    f32x4 acc = {0.f, 0.f, 0.f, 0.f};

    #pragma unroll 4
    for (int k0 = 0; k0 < Dm; k0 += 32) {
        bf16x8 a;
        if constexpr (A_BF16) {
            const __bf16* Ab = (const __bf16*)Aptr;
            a = *(const bf16x8*)(Ab + (row0 + r) * Dm + k0 + (kg << 3));
        } else {
            const float* Af = (const float*)Aptr;
            float4 a0 = *(const float4*)(Af + (row0 + r) * Dm + k0 + (kg << 3));
            float4 a1 = *(const float4*)(Af + (row0 + r) * Dm + k0 + (kg << 3) + 4);
            a[0] = (__bf16)a0.x; a[1] = (__bf16)a0.y; a[2] = (__bf16)a0.z; a[3] = (__bf16)a0.w;
            a[4] = (__bf16)a1.x; a[5] = (__bf16)a1.y; a[6] = (__bf16)a1.z; a[7] = (__bf16)a1.w;
        }
        bf16x8 b;
        #pragma unroll
        for (int t = 0; t < 8; ++t)
            b[t] = (__bf16)Bp[(k0 + t) * Dm];
        acc = __builtin_amdgcn_mfma_f32_16x16x32_bf16(a, b, acc, 0, 0, 0);
    }

    int orow = row0 + (kg << 2);
    float bb = bias[col0 + r];
    #pragma unroll
    for (int t = 0; t < 4; ++t) {
        float v = acc[t] + bb;
        O[(orow + t) * Dm + col0 + r] = v;
        if (m == 1)
            Kbf[(orow + t) * Dm + col0 + r] = (__bf16)v;
    }
}

// ---------------- z-pass: lane = i, Q-row in VGPRs, K rows via bf16 scalar bursts ----------------
// grid 512 = 8 heads * 8 i-tiles(64) * 8 j-tiles(64). 512 thr = 8 waves; wave w: 8 j's.
// Per j: 8 s_load_dwordx4 (64 bf16), unpack 64 VALU, compute 128 VALU.
__global__ __launch_bounds__(512) void zfast_kernel(
    const float* __restrict__ Q, const __bf16* __restrict__ Kbf,
    const float* __restrict__ mask, const float* __restrict__ gamma,
    const float* __restrict__ alpha,
    __bf16* __restrict__ zpb, float* __restrict__ Zpart)
{
    int blk = blockIdx.x;
    int h  = blk >> 6;
    int it = (blk >> 3) & 7;
    int jt = blk & 7;
    int i0 = it << 6;
    int j0 = jt << 6;
    int c0 = h << 6;

    int u = threadIdx.x;
    int w = u >> 6, lane = u & 63;

    __shared__ float zsT[64][65];
    __shared__ float partial[8][64];

    float qreg[64];
    #pragma unroll
    for (int t = 0; t < 16; ++t) {
        float4 qv = *(const float4*)(Q + (i0 + lane) * Dm + c0 + (t << 2));
        qreg[4 * t + 0] = qv.x; qreg[4 * t + 1] = qv.y;
        qreg[4 * t + 2] = qv.z; qreg[4 * t + 3] = qv.w;
    }

    float sc = 1.0f / (gamma[0] * 8.0f);
    float al = alpha[0];

    int jb = __builtin_amdgcn_readfirstlane(w << 3);
    const uint4* kb0 = (const uint4*)(Kbf + (j0 + jb) * Dm + c0);
    const int RSTRIDE = Dm * 2 / 16;   // uint4 per bf16 row = 64

    float zsum = 0.f;

    uint4 kA[8], kB[8];
    #pragma unroll
    for (int t = 0; t < 8; ++t) kA[t] = kb0[t];

    auto compute_row = [&](const uint4 (&kr)[8], int jj) {
        float a0 = 0.f, a1 = 0.f, a2 = 0.f, a3 = 0.f;
        #pragma unroll
        for (int t = 0; t < 8; ++t) {
            int d = t << 3;
            a0 += fabsf(qreg[d + 0] - bflo(kr[t].x));
            a1 += fabsf(qreg[d + 1] - bfhi(kr[t].x));
            a2 += fabsf(qreg[d + 2] - bflo(kr[t].y));
            a3 += fabsf(qreg[d + 3] - bfhi(kr[t].y));
            a0 += fabsf(qreg[d + 4] - bflo(kr[t].z));
            a1 += fabsf(qreg[d + 5] - bfhi(kr[t].z));
            a2 += fabsf(qreg[d + 6] - bflo(kr[t].w));
            a3 += fabsf(qreg[d + 7] - bfhi(kr[t].w));
        }
        int j = j0 + jb + jj;
        float madd = (1.0f - mask[j]) * 1e6f;
        float zpv = fmaxf((a0 + a1 + a2 + a3) * sc - al, 0.0f) + madd;
        float zr = (float)(__bf16)zpv;      // round now so Zsum cancels exactly
        zsT[jb + jj][lane] = zr;
        zsum += zr;
    };

    #pragma unroll
    for (int jp = 0; jp < 8; jp += 2) {
        {   // prefetch row jp+1
            const uint4* kn = kb0 + (jp + 1) * RSTRIDE;
            #pragma unroll
            for (int t = 0; t < 8; ++t) kB[t] = kn[t];
        }
        compute_row(kA, jp);
        if (jp + 2 < 8) {   // prefetch row jp+2
            const uint4* kn = kb0 + (jp + 2) * RSTRIDE;
            #pragma unroll
            for (int t = 0; t < 8; ++t) kA[t] = kn[t];
        }
        compute_row(kB, jp + 1);
    }

    partial[w][lane] = zsum;
    __syncthreads();

    if (u < 64) {
        float zs8 = 0.f;
        #pragma unroll
        for (int p = 0; p < 8; ++p) zs8 += partial[p][u];
        Zpart[((h << 9) + i0 + u) * 8 + jt] = zs8;
    }

    // transposed zp write: thread -> row il, 8 consecutive j as bf16 (16B)
    {
        int il = u >> 3;
        int jg = (u & 7) << 3;
        bf16x8 o;
        #pragma unroll
        for (int q = 0; q < 8; ++q) o[q] = (__bf16)zsT[jg + q][il];
        *(bf16x8*)(zpb + ((h << 9) + i0 + il) * S + j0 + jg) = o;
    }
}

// ---------------- ctx: ctx[i][d] = sum_j max(v,z') - Zsum; z' bf16 scalar bursts ----------------
// grid 512 = 8 heads * 64 i-tiles(8). 512 thr = 8 waves; lane = d; wave slice 16 j per cch.
__global__ __launch_bounds__(512) void ctx_kernel(
    const float* __restrict__ V, const __bf16* __restrict__ zpb,
    const float* __restrict__ Zpart, __bf16* __restrict__ ctxb)
{
    int blk = blockIdx.x;
    int h = blk >> 6;
    int it = blk & 63;
    int i0 = it << 3;
    int c0 = h << 6;
    int u = threadIdx.x;
    int w = u >> 6, lane = u & 63;

    __shared__ float part[8][8][64];

    int wu = __builtin_amdgcn_readfirstlane(w);
    const int ZSTRIDE = S * 2 / 16;    // uint4 per bf16 z-row = 64
    float acc[8][4] = {};

    #pragma unroll
    for (int cch = 0; cch < 4; ++cch) {
        int jg = (cch << 7) + (wu << 4);                    // uniform
        // V: per-lane VMEM (vmcnt) — issue first, hides under SMEM wait
        float vv[16];
        #pragma unroll
        for (int t = 0; t < 16; ++t)
            vv[t] = V[(jg + t) * Dm + c0 + lane];

        // z': 8 rows x 16 bf16 = 16 uint4 scalar loads (one burst)
        const uint4* zb = (const uint4*)(zpb + ((h << 9) + i0) * S + jg);
        uint4 zU[16];
        #pragma unroll
        for (int ii = 0; ii < 8; ++ii) {
            zU[(ii << 1) + 0] = zb[ii * ZSTRIDE + 0];
            zU[(ii << 1) + 1] = zb[ii * ZSTRIDE + 1];
        }

        #pragma unroll
        for (int ii = 0; ii < 8; ++ii) {
            #pragma unroll
            for (int b = 0; b < 2; ++b) {
                uint4 zu = zU[(ii << 1) + b];
                int j8 = b << 3;
                acc[ii][0] += fmaxf(vv[j8 + 0], bflo(zu.x));
                acc[ii][1] += fmaxf(vv[j8 + 1], bfhi(zu.x));
                acc[ii][2] += fmaxf(vv[j8 + 2], bflo(zu.y));
                acc[ii][3] += fmaxf(vv[j8 + 3], bfhi(zu.y));
                acc[ii][0] += fmaxf(vv[j8 + 4], bflo(zu.z));
                acc[ii][1] += fmaxf(vv[j8 + 5], bfhi(zu.z));
                acc[ii][2] += fmaxf(vv[j8 + 6], bflo(zu.w));
                acc[ii][3] += fmaxf(vv[j8 + 7], bfhi(zu.w));
            }
        }
    }

    #pragma unroll
    for (int ii = 0; ii < 8; ++ii)
        part[w][ii][lane] = (acc[ii][0] + acc[ii][1]) + (acc[ii][2] + acc[ii][3]);
    __syncthreads();

    {
        int ii = u >> 6;
        float s = 0.f;
        #pragma unroll
        for (int ww = 0; ww < 8; ++ww) s += part[ww][ii][lane];
        float zsum = 0.f;
        const float* zpr = Zpart + ((h << 9) + (i0 + ii)) * 8;
        #pragma unroll
        for (int p = 0; p < 8; ++p) zsum += zpr[p];
        ctxb[(i0 + ii) * Dm + c0 + lane] = (__bf16)(s - zsum);
    }
}

extern "C" void kernel_launch(void* const* d_in, const int* in_sizes, int n_in,
                              void* d_out, int out_size, void* d_ws, size_t ws_size,
                              hipStream_t stream) {
    const float* hs    = (const float*)d_in[0];
    const float* mask  = (const float*)d_in[1];
    const float* Wq    = (const float*)d_in[2];
    const float* bq    = (const float*)d_in[3];
    const float* Wk    = (const float*)d_in[4];
    const float* bk    = (const float*)d_in[5];
    const float* Wv    = (const float*)d_in[6];
    const float* bv    = (const float*)d_in[7];
    const float* Wo    = (const float*)d_in[8];
    const float* bo    = (const float*)d_in[9];
    const float* gamma = (const float*)d_in[10];
    const float* alpha = (const float*)d_in[11];
    float* out = (float*)d_out;

    char* base = (char*)d_ws;
    __bf16* zpb   = (__bf16*)(base);                              // 4 MB
    float*  Zpart = (float*)(base + (4u << 20));                  // 128 KB
    float*  Qb    = (float*)(base + (4u << 20) + (128u << 10));   // 1 MB
    float*  Kb    = Qb + S * Dm;                                  // 1 MB
    float*  Vb    = Kb + S * Dm;                                  // 1 MB
    __bf16* Kbf   = (__bf16*)(Vb + S * Dm);                       // 0.5 MB
    __bf16* Cbf   = Kbf + S * Dm;                                 // 0.5 MB

    hipLaunchKernelGGL((gemm_icvt<false>), dim3(768), dim3(256), 0, stream,
                       (const void*)hs, Wq, Wk, Wv, bq, bk, bv, Qb, Kb, Vb, Kbf);
    hipLaunchKernelGGL(zfast_kernel, dim3(512), dim3(512), 0, stream,
                       Qb, Kbf, mask, gamma, alpha, zpb, Zpart);
    hipLaunchKernelGGL(ctx_kernel, dim3(512), dim3(512), 0, stream,
                       Vb, zpb, Zpart, Cbf);
    hipLaunchKernelGGL((gemm_icvt<true>), dim3(256), dim3(256), 0, stream,
                       (const void*)Cbf, Wo, Wo, Wo, bo, bo, bo, out, out, out, Kbf);
}